// Round 4
// baseline (3513.178 us; speedup 1.0000x reference)
//
#include <hip/hip_runtime.h>
#include <hip/hip_bf16.h>

typedef __bf16 bf16x8 __attribute__((ext_vector_type(8)));
typedef __bf16 bf16x4 __attribute__((ext_vector_type(4)));
typedef float floatx4 __attribute__((ext_vector_type(4)));
typedef unsigned long long ull;

#define AGT __HIP_MEMORY_SCOPE_AGENT

__device__ __forceinline__ ull cload(const ull* p) {
    return __hip_atomic_load(const_cast<ull*>(p), __ATOMIC_RELAXED, AGT);
}
__device__ __forceinline__ void cstore(ull* p, ull v) {
    __hip_atomic_store(p, v, __ATOMIC_RELAXED, AGT);
}
__device__ __forceinline__ float fsig(float x) { return 1.f / (1.f + __expf(-x)); }
__device__ __forceinline__ float ftanh(float x) { return 1.f - 2.f / (__expf(2.f * x) + 1.f); }

// ---------------- prep kernels ----------------

// x (65536,100) fp32 -> Xb (65536,128) bf16 padded; 8 outputs/thread, 16B stores
__global__ __launch_bounds__(256) void prep_x(const float* __restrict__ x,
                                              __hip_bfloat16* __restrict__ Xb) {
    int t = blockIdx.x * 256 + threadIdx.x;      // 0..1048575
    int row = t >> 4, c8 = (t & 15) * 8;
    union { __hip_bfloat16 h[8]; uint4 u; } pk;
#pragma unroll
    for (int j = 0; j < 8; j++) {
        int col = c8 + j;
        float v = (col < 100) ? x[row * 100 + col] : 0.f;
        pk.h[j] = __float2bfloat16(v);
    }
    *reinterpret_cast<uint4*>(Xb + (size_t)row * 128 + c8) = pk.u;
}

// Wcat (1536 x ldW) bf16 = [Wih (padded to K1) | Whh(1536x384)]
__global__ __launch_bounds__(256) void prep_wcat(const float* __restrict__ Wih, int Kin, int K1,
                                                 const float* __restrict__ Whh,
                                                 __hip_bfloat16* __restrict__ Wcat, int ldW) {
    int k = blockIdx.x * 256 + threadIdx.x;
    int row = blockIdx.y;
    if (k >= ldW) return;
    float v;
    if (k < K1) v = (k < Kin) ? Wih[row * Kin + k] : 0.f;
    else        v = Whh[row * 384 + (k - K1)];
    Wcat[row * ldW + k] = __float2bfloat16(v);
}

// zero slot 0 of H0b, H1b (bf16 256x384) and the barrier counters
__global__ __launch_bounds__(256) void init_zero(__hip_bfloat16* __restrict__ H0b,
                                                 __hip_bfloat16* __restrict__ H1b,
                                                 unsigned* __restrict__ bar) {
    int i = blockIdx.x * 256 + threadIdx.x;          // 0..98303
    __hip_bfloat16 z = __float2bfloat16(0.f);
    H0b[i] = z; H1b[i] = z;
    if (i < 1024) bar[i] = 0u;
}

// Wtmp (10,512) = W3 (10,1024) @ W2 (1024,512)
__global__ __launch_bounds__(256) void wtmp_k(const float* __restrict__ W3,
                                              const float* __restrict__ W2,
                                              float* __restrict__ Wtmp) {
    int idx = blockIdx.x * 256 + threadIdx.x;
    int j = idx / 512, i = idx % 512;
    float acc = 0.f;
    for (int q = 0; q < 1024; q++) acc += W3[j * 1024 + q] * W2[q * 512 + i];
    Wtmp[idx] = acc;
}

// Weff (10,384) = Wtmp (10,512) @ W1 (512,384)
__global__ __launch_bounds__(256) void weff_k(const float* __restrict__ Wtmp,
                                              const float* __restrict__ W1,
                                              float* __restrict__ Weff) {
    int idx = blockIdx.x * 256 + threadIdx.x;
    if (idx >= 3840) return;
    int j = idx / 384, i = idx % 384;
    float acc = 0.f;
    for (int q = 0; q < 512; q++) acc += Wtmp[j * 512 + q] * W1[q * 384 + i];
    Weff[idx] = acc;
}

// beff (10) = b3 + W3@b2 + Wtmp@b1
__global__ void beff_k(const float* __restrict__ W3, const float* __restrict__ b2,
                       const float* __restrict__ Wtmp, const float* __restrict__ b1,
                       const float* __restrict__ b3, float* __restrict__ beff) {
    int j = threadIdx.x;
    if (j >= 10) return;
    float acc = b3[j];
    for (int q = 0; q < 1024; q++) acc += W3[j * 1024 + q] * b2[q];
    for (int q = 0; q < 512; q++)  acc += Wtmp[j * 512 + q] * b1[q];
    beff[j] = acc;
}

// ---------------- fused persistent LSTM (both layers in one block) ----------------
// 96 blocks = 8 groups (g = blockIdx&7, 32 batch rows) x 12 d-slices
// (bsub = blockIdx>>3, gate dims [bsub*32, bsub*32+32) across 4 gates; wave=gate).
// Iteration t: L0 step t (recurrent h0(t)) + L1 step t-1 (input h0(t), recurrent
// h1(t-1)) — h0(t) staged ONCE serves both. One 12-block barrier per iteration.
// Cross-block h traffic via relaxed agent atomics (coherent, bypass stale L2).

__device__ __forceinline__ bf16x8 lds_frag(const short* As, int r, int k) {
    const short* p = As + r * 388 + k;
    bf16x4 lo = *reinterpret_cast<const bf16x4*>(p);
    bf16x4 hi = *reinterpret_cast<const bf16x4*>(p + 4);
    return __builtin_shufflevector(lo, hi, 0, 1, 2, 3, 4, 5, 6, 7);
}

// stage 32 rows x 384 bf16 (contiguous 24576B) into LDS (row stride 388 shorts)
__device__ __forceinline__ void stage(short* As, const ull* src, int tid) {
#pragma unroll
    for (int i = 0; i < 12; i++) {
        int q = tid + 256 * i;          // 0..3071 (96 ull per row)
        int row = q / 96;
        int c8 = q - row * 96;
        ull v = cload(src + q);
        *reinterpret_cast<ull*>(As + row * 388 + c8 * 4) = v;
    }
}

__global__ __launch_bounds__(256, 1) void lstm_fused(
    const __hip_bfloat16* __restrict__ Xb,
    const __hip_bfloat16* __restrict__ Wcat0,   // 1536 x 512
    const __hip_bfloat16* __restrict__ Wcat1,   // 1536 x 768
    const float* __restrict__ bih0, const float* __restrict__ bhh0,
    const float* __restrict__ bih1, const float* __restrict__ bhh1,
    __hip_bfloat16* __restrict__ H0, __hip_bfloat16* __restrict__ H1,
    unsigned* __restrict__ bar)
{
    __shared__ __align__(16) char smem[49664];
    short* As0   = (short*)smem;             // region A: h0 stage / gbuf1
    short* As1   = (short*)(smem + 24832);   // region B: gbuf0 / h1 stage
    float* gbuf0 = (float*)(smem + 24832);
    float* gbuf1 = (float*)smem;

    int tid = threadIdx.x;
    int g = blockIdx.x & 7;
    int bsub = blockIdx.x >> 3;
    unsigned* ctr = bar + g * 64;

    int lane = tid & 63, wv = tid >> 6;
    int lane15 = lane & 15;
    int koff = (lane >> 4) * 8;

    // ---- register-resident weights: L0 2x16 frags, L1 2x24 frags ----
    bf16x8 bf0[2][16], bf1[2][24];
#pragma unroll
    for (int nt = 0; nt < 2; nt++) {
        const __hip_bfloat16* w0 = Wcat0 + (size_t)(wv * 384 + bsub * 32 + nt * 16 + lane15) * 512;
        const __hip_bfloat16* w1 = Wcat1 + (size_t)(wv * 384 + bsub * 32 + nt * 16 + lane15) * 768;
#pragma unroll
        for (int kk = 0; kk < 16; kk++)
            bf0[nt][kk] = *reinterpret_cast<const bf16x8*>(w0 + kk * 32 + koff);
#pragma unroll
        for (int kk = 0; kk < 24; kk++)
            bf1[nt][kk] = *reinterpret_cast<const bf16x8*>(w1 + kk * 32 + koff);
    }

    // ---- cell-thread state: m = tid>>3 (0..31), d0 = (tid&7)*4 ----
    int m = tid >> 3, d0 = (tid & 7) * 4;
    int dgl = bsub * 32 + d0;
    float bb0[4][4], bb1[4][4];
#pragma unroll
    for (int j = 0; j < 4; j++)
#pragma unroll
        for (int jj = 0; jj < 4; jj++) {
            bb0[j][jj] = bih0[j * 384 + dgl + jj] + bhh0[j * 384 + dgl + jj];
            bb1[j][jj] = bih1[j * 384 + dgl + jj] + bhh1[j * 384 + dgl + jj];
        }
    float c0[4] = {0.f, 0.f, 0.f, 0.f}, c1[4] = {0.f, 0.f, 0.f, 0.f};

    const __hip_bfloat16* XbRow = Xb + (size_t)(g * 32 + lane15) * 128 + koff;
    ull* h0out = reinterpret_cast<ull*>(H0 + (size_t)(g * 32 + m) * 384 + dgl);
    ull* h1out = reinterpret_cast<ull*>(H1 + (size_t)(g * 32 + m) * 384 + dgl);
    const ull* h0src = reinterpret_cast<const ull*>(H0 + (size_t)g * 12288);
    const ull* h1src = reinterpret_cast<const ull*>(H1 + (size_t)g * 12288);
    int r0 = (lane >> 4) * 4, ccol = lane15;

#pragma unroll 1
    for (int t = 0; t <= 256; t++) {
        // ---- wait: all 12 blocks of group done iteration t-1 ----
        if (tid == 0) {
            unsigned lim = 12u * (unsigned)t;
            while (__hip_atomic_load(ctr, __ATOMIC_RELAXED, AGT) < lim)
                __builtin_amdgcn_s_sleep(1);
        }
        __syncthreads();
        asm volatile("" ::: "memory");

        // ---- Xb fragment loads issued first (latency overlaps stage) ----
        bf16x8 ax[2][4];
        if (t < 256) {
            const __hip_bfloat16* A1p = XbRow + (size_t)t * 32768;
#pragma unroll
            for (int mt = 0; mt < 2; mt++)
#pragma unroll
                for (int kk = 0; kk < 4; kk++)
                    ax[mt][kk] = *reinterpret_cast<const bf16x8*>(A1p + mt * 2048 + kk * 32);
        }

        // ---- stage h0(t) -> region A (serves L0 recurrent + L1 input) ----
        stage(As0, h0src + (size_t)t * 12288, tid);
        __syncthreads();

        if (t < 256) {
            // ---- layer-0 gates ----
            floatx4 acc[2][2];
#pragma unroll
            for (int mt = 0; mt < 2; mt++)
#pragma unroll
                for (int nt = 0; nt < 2; nt++) acc[mt][nt] = floatx4{0.f, 0.f, 0.f, 0.f};
#pragma unroll
            for (int kk = 0; kk < 4; kk++)
#pragma unroll
                for (int mt = 0; mt < 2; mt++) {
                    acc[mt][0] = __builtin_amdgcn_mfma_f32_16x16x32_bf16(ax[mt][kk], bf0[0][kk], acc[mt][0], 0, 0, 0);
                    acc[mt][1] = __builtin_amdgcn_mfma_f32_16x16x32_bf16(ax[mt][kk], bf0[1][kk], acc[mt][1], 0, 0, 0);
                }
#pragma unroll
            for (int kk = 0; kk < 12; kk++)
#pragma unroll
                for (int mt = 0; mt < 2; mt++) {
                    bf16x8 a = lds_frag(As0, mt * 16 + lane15, kk * 32 + koff);
                    acc[mt][0] = __builtin_amdgcn_mfma_f32_16x16x32_bf16(a, bf0[0][4 + kk], acc[mt][0], 0, 0, 0);
                    acc[mt][1] = __builtin_amdgcn_mfma_f32_16x16x32_bf16(a, bf0[1][4 + kk], acc[mt][1], 0, 0, 0);
                }
#pragma unroll
            for (int mt = 0; mt < 2; mt++)
#pragma unroll
                for (int nt = 0; nt < 2; nt++)
#pragma unroll
                    for (int r = 0; r < 4; r++)
                        gbuf0[wv * 1056 + (mt * 16 + r0 + r) * 33 + nt * 16 + ccol] = acc[mt][nt][r];
            __syncthreads();

            // ---- cell 0: h0(t+1) ----
            union { ull u; __hip_bfloat16 h[4]; } pk;
#pragma unroll
            for (int jj = 0; jj < 4; jj++) {
                float gi = gbuf0[0 * 1056 + m * 33 + d0 + jj] + bb0[0][jj];
                float gf = gbuf0[1 * 1056 + m * 33 + d0 + jj] + bb0[1][jj];
                float gg = gbuf0[2 * 1056 + m * 33 + d0 + jj] + bb0[2][jj];
                float go = gbuf0[3 * 1056 + m * 33 + d0 + jj] + bb0[3][jj];
                float c = fsig(gf) * c0[jj] + fsig(gi) * ftanh(gg);
                c0[jj] = c;
                pk.h[jj] = __float2bfloat16(fsig(go) * ftanh(c));
            }
            cstore(h0out + (size_t)(t + 1) * 12288, pk.u);
        }
        __syncthreads();   // gbuf0 reads done; h0 stores drained (vmcnt 0)

        if (t > 0) {
            // ---- stage h1(t-1) -> region B ----
            stage(As1, h1src + (size_t)(t - 1) * 12288, tid);
            __syncthreads();

            // ---- layer-1 gates: input h0(t) [A], recurrent h1(t-1) [B] ----
            floatx4 acc[2][2];
#pragma unroll
            for (int mt = 0; mt < 2; mt++)
#pragma unroll
                for (int nt = 0; nt < 2; nt++) acc[mt][nt] = floatx4{0.f, 0.f, 0.f, 0.f};
#pragma unroll
            for (int kk = 0; kk < 12; kk++)
#pragma unroll
                for (int mt = 0; mt < 2; mt++) {
                    bf16x8 a = lds_frag(As0, mt * 16 + lane15, kk * 32 + koff);
                    acc[mt][0] = __builtin_amdgcn_mfma_f32_16x16x32_bf16(a, bf1[0][kk], acc[mt][0], 0, 0, 0);
                    acc[mt][1] = __builtin_amdgcn_mfma_f32_16x16x32_bf16(a, bf1[1][kk], acc[mt][1], 0, 0, 0);
                }
#pragma unroll
            for (int kk = 0; kk < 12; kk++)
#pragma unroll
                for (int mt = 0; mt < 2; mt++) {
                    bf16x8 a = lds_frag(As1, mt * 16 + lane15, kk * 32 + koff);
                    acc[mt][0] = __builtin_amdgcn_mfma_f32_16x16x32_bf16(a, bf1[0][12 + kk], acc[mt][0], 0, 0, 0);
                    acc[mt][1] = __builtin_amdgcn_mfma_f32_16x16x32_bf16(a, bf1[1][12 + kk], acc[mt][1], 0, 0, 0);
                }
            __syncthreads();   // all region-A frag reads done before gbuf1 writes
#pragma unroll
            for (int mt = 0; mt < 2; mt++)
#pragma unroll
                for (int nt = 0; nt < 2; nt++)
#pragma unroll
                    for (int r = 0; r < 4; r++)
                        gbuf1[wv * 1056 + (mt * 16 + r0 + r) * 33 + nt * 16 + ccol] = acc[mt][nt][r];
            __syncthreads();

            // ---- cell 1: h1(t) = y1(t-1) ----
            union { ull u; __hip_bfloat16 h[4]; } pk;
#pragma unroll
            for (int jj = 0; jj < 4; jj++) {
                float gi = gbuf1[0 * 1056 + m * 33 + d0 + jj] + bb1[0][jj];
                float gf = gbuf1[1 * 1056 + m * 33 + d0 + jj] + bb1[1][jj];
                float gg = gbuf1[2 * 1056 + m * 33 + d0 + jj] + bb1[2][jj];
                float go = gbuf1[3 * 1056 + m * 33 + d0 + jj] + bb1[3][jj];
                float c = fsig(gf) * c1[jj] + fsig(gi) * ftanh(gg);
                c1[jj] = c;
                pk.h[jj] = __float2bfloat16(fsig(go) * ftanh(c));
            }
            cstore(h1out + (size_t)t * 12288, pk.u);
        }
        __syncthreads();   // drain h1 stores (and gbuf1 reads) before signal
        if (tid == 0)
            __hip_atomic_fetch_add(ctr, 1u, __ATOMIC_RELAXED, AGT);
    }
}

// ---------------- emissions: EM (65536,10) = H1 (65536,384) @ Weff^T + beff ----------------
__global__ __launch_bounds__(256) void em_kernel(const __hip_bfloat16* __restrict__ H1,
                                                 const float* __restrict__ Weff,
                                                 const float* __restrict__ beff,
                                                 float* __restrict__ em) {
    __shared__ __hip_bfloat16 At[256 * 68];
    __shared__ float Wt[640];
    __shared__ float bf[10];
    int tid = threadIdx.x;
    int row0 = blockIdx.x * 256;
    if (tid < 10) bf[tid] = beff[tid];
    float acc[10];
#pragma unroll
    for (int j = 0; j < 10; j++) acc[j] = 0.f;

    for (int kt = 0; kt < 384; kt += 64) {
        __syncthreads();
#pragma unroll
        for (int q = 0; q < 16; q++) {
            int flat = q * 256 + tid;
            int r = flat >> 4;
            int k4 = flat & 15;
            const __hip_bfloat16* src = H1 + (size_t)(row0 + r) * 384 + kt + k4 * 4;
            *reinterpret_cast<uint2*>(&At[r * 68 + k4 * 4]) =
                *reinterpret_cast<const uint2*>(src);
        }
        for (int q = tid; q < 640; q += 256) {
            int j = q >> 6, k = q & 63;
            Wt[q] = Weff[j * 384 + kt + k];
        }
        __syncthreads();
        for (int k = 0; k < 64; k++) {
            float a = __bfloat162float(At[tid * 68 + k]);
#pragma unroll
            for (int j = 0; j < 10; j++) acc[j] += a * Wt[j * 64 + k];
        }
    }
#pragma unroll
    for (int j = 0; j < 10; j++) em[(size_t)(row0 + tid) * 10 + j] = acc[j] + bf[j];
}

// ---------------- CRF: one block (64 thr) per sequence ----------------
__global__ __launch_bounds__(64) void crf_kernel(const float* __restrict__ em,
                                                 const int* __restrict__ tags,
                                                 const float* __restrict__ start_t,
                                                 const float* __restrict__ end_t,
                                                 const float* __restrict__ trans,
                                                 float* __restrict__ nll) {
    int s = blockIdx.x;
    int l = threadIdx.x;
    __shared__ float tr[100];
    __shared__ float aA[16], aB[16];
    if (l < 100) tr[l] = trans[l];
    if (l < 36)  tr[l + 64] = trans[l + 64];
    __syncthreads();

    float part = 0.f;
    for (int b = l; b < 256; b += 64) {
        int tg = tags[s * 256 + b];
        part += em[(size_t)(s * 256 + b) * 10 + tg];
        if (b > 0) {
            int tp = tags[s * 256 + b - 1];
            part += tr[tp * 10 + tg];
        }
    }
    for (int off = 32; off > 0; off >>= 1) part += __shfl_down(part, off);

    if (l < 10) aA[l] = start_t[l] + em[(size_t)(s * 256) * 10 + l];
    __syncthreads();
    for (int b = 1; b < 256; b++) {
        const float* rb = (b & 1) ? aA : aB;
        float* wb = (b & 1) ? aB : aA;
        if (l < 10) {
            float m = -1e30f;
            for (int i = 0; i < 10; i++) m = fmaxf(m, rb[i] + tr[i * 10 + l]);
            float ssum = 0.f;
            for (int i = 0; i < 10; i++) ssum += __expf(rb[i] + tr[i * 10 + l] - m);
            wb[l] = em[(size_t)(s * 256 + b) * 10 + l] + m + __logf(ssum);
        }
        __syncthreads();
    }
    if (l == 0) {
        const float* af = aB;
        float m = -1e30f;
        for (int i = 0; i < 10; i++) m = fmaxf(m, af[i] + end_t[i]);
        float ssum = 0.f;
        for (int i = 0; i < 10; i++) ssum += __expf(af[i] + end_t[i] - m);
        float logZ = m + __logf(ssum);
        float score = part + start_t[tags[s * 256]] + end_t[tags[s * 256 + 255]];
        nll[s] = logZ - score;
    }
}

__global__ __launch_bounds__(256) void reduce_k(const float* __restrict__ nll,
                                                float* __restrict__ out) {
    __shared__ float sm[256];
    int t = threadIdx.x;
    sm[t] = nll[t];
    __syncthreads();
    for (int s = 128; s > 0; s >>= 1) {
        if (t < s) sm[t] += sm[t + s];
        __syncthreads();
    }
    if (t == 0) out[0] = sm[0];
}

// ---------------- host ----------------

extern "C" void kernel_launch(void* const* d_in, const int* in_sizes, int n_in,
                              void* d_out, int out_size, void* d_ws, size_t ws_size,
                              hipStream_t stream) {
    const float* x     = (const float*)d_in[0];
    const int*   tags  = (const int*)d_in[2];
    const float* Wih0  = (const float*)d_in[3];
    const float* Whh0  = (const float*)d_in[4];
    const float* bih0  = (const float*)d_in[5];
    const float* bhh0  = (const float*)d_in[6];
    const float* Wih1  = (const float*)d_in[7];
    const float* Whh1  = (const float*)d_in[8];
    const float* bih1  = (const float*)d_in[9];
    const float* bhh1  = (const float*)d_in[10];
    const float* W1    = (const float*)d_in[11];
    const float* b1    = (const float*)d_in[12];
    const float* W2    = (const float*)d_in[13];
    const float* b2    = (const float*)d_in[14];
    const float* W3    = (const float*)d_in[15];
    const float* b3    = (const float*)d_in[16];
    const float* start_t = (const float*)d_in[17];
    const float* end_t   = (const float*)d_in[18];
    const float* trans   = (const float*)d_in[19];

    char* ws = (char*)d_ws;
    size_t off = 0;
    auto alloc = [&](size_t bytes) { void* p = ws + off; off += (bytes + 255) & ~(size_t)255; return p; };

    __hip_bfloat16* Xb    = (__hip_bfloat16*)alloc((size_t)65536 * 128 * 2);
    __hip_bfloat16* Wcat0 = (__hip_bfloat16*)alloc((size_t)1536 * 512 * 2);
    __hip_bfloat16* Wcat1 = (__hip_bfloat16*)alloc((size_t)1536 * 768 * 2);
    __hip_bfloat16* H0b   = (__hip_bfloat16*)alloc((size_t)257 * 98304 * 2);
    __hip_bfloat16* H1b   = (__hip_bfloat16*)alloc((size_t)257 * 98304 * 2);
    float* EM   = (float*)alloc((size_t)65536 * 10 * 4);
    float* Wtmp = (float*)alloc((size_t)10 * 512 * 4);
    float* Weff = (float*)alloc((size_t)10 * 384 * 4);
    float* beff = (float*)alloc(256);
    float* nll  = (float*)alloc(256 * 4);
    unsigned* bar = (unsigned*)alloc(1024 * 4);

    // prep
    prep_x<<<4096, 256, 0, stream>>>(x, Xb);
    prep_wcat<<<dim3(2, 1536), 256, 0, stream>>>(Wih0, 100, 128, Whh0, Wcat0, 512);
    prep_wcat<<<dim3(3, 1536), 256, 0, stream>>>(Wih1, 384, 384, Whh1, Wcat1, 768);
    init_zero<<<384, 256, 0, stream>>>(H0b, H1b, bar);
    wtmp_k<<<20, 256, 0, stream>>>(W3, W2, Wtmp);
    weff_k<<<15, 256, 0, stream>>>(Wtmp, W1, Weff);
    beff_k<<<1, 64, 0, stream>>>(W3, b2, Wtmp, b1, b3, beff);

    // both LSTM layers fused, pipelined in one persistent kernel
    lstm_fused<<<96, 256, 0, stream>>>(Xb, Wcat0, Wcat1,
                                       bih0, bhh0, bih1, bhh1,
                                       H0b, H1b, bar);

    // emissions + CRF
    em_kernel<<<256, 256, 0, stream>>>(H1b + 98304, Weff, beff, EM);
    crf_kernel<<<256, 64, 0, stream>>>(EM, tags, start_t, end_t, trans, nll);
    reduce_k<<<1, 256, 0, stream>>>(nll, (float*)d_out);
}

// Round 7
// 2621.500 us; speedup vs baseline: 1.3401x; 1.3401x over previous
//
#include <hip/hip_runtime.h>
#include <hip/hip_bf16.h>

typedef __bf16 bf16x8 __attribute__((ext_vector_type(8)));
typedef __bf16 bf16x4 __attribute__((ext_vector_type(4)));
typedef float floatx4 __attribute__((ext_vector_type(4)));
typedef unsigned long long ull;

#define AGT __HIP_MEMORY_SCOPE_AGENT

// Relaxed agent-scope atomics: compile to sc1 (device-scope) loads/stores that
// bypass the non-coherent L1/L2 and hit the coherent L3. NO acquire/release
// anywhere in the hot loop (agent-acquire = L2 invalidate per poll on gfx950).
__device__ __forceinline__ ull cload(const ull* p) {
    return __hip_atomic_load(const_cast<ull*>(p), __ATOMIC_RELAXED, AGT);
}
__device__ __forceinline__ void cstore(ull* p, ull v) {
    __hip_atomic_store(p, v, __ATOMIC_RELAXED, AGT);
}
__device__ __forceinline__ unsigned fload(const unsigned* p) {
    return __hip_atomic_load(const_cast<unsigned*>(p), __ATOMIC_RELAXED, AGT);
}
__device__ __forceinline__ float fsig(float x) { return 1.f / (1.f + __expf(-x)); }
__device__ __forceinline__ float ftanh(float x) { return 1.f - 2.f / (__expf(2.f * x) + 1.f); }

// ---------------- prep kernels ----------------

__global__ __launch_bounds__(256) void prep_x(const float* __restrict__ x,
                                              __hip_bfloat16* __restrict__ Xb) {
    int t = blockIdx.x * 256 + threadIdx.x;
    int row = t >> 4, c8 = (t & 15) * 8;
    union { __hip_bfloat16 h[8]; uint4 u; } pk;
#pragma unroll
    for (int j = 0; j < 8; j++) {
        int col = c8 + j;
        float v = (col < 100) ? x[row * 100 + col] : 0.f;
        pk.h[j] = __float2bfloat16(v);
    }
    *reinterpret_cast<uint4*>(Xb + (size_t)row * 128 + c8) = pk.u;
}

__global__ __launch_bounds__(256) void prep_wcat(const float* __restrict__ Wih, int Kin, int K1,
                                                 const float* __restrict__ Whh,
                                                 __hip_bfloat16* __restrict__ Wcat, int ldW) {
    int k = blockIdx.x * 256 + threadIdx.x;
    int row = blockIdx.y;
    if (k >= ldW) return;
    float v;
    if (k < K1) v = (k < Kin) ? Wih[row * Kin + k] : 0.f;
    else        v = Whh[row * 384 + (k - K1)];
    Wcat[row * ldW + k] = __float2bfloat16(v);
}

__global__ __launch_bounds__(256) void init_zero(__hip_bfloat16* __restrict__ H0b,
                                                 __hip_bfloat16* __restrict__ H1b,
                                                 unsigned* __restrict__ bar) {
    int i = blockIdx.x * 256 + threadIdx.x;
    __hip_bfloat16 z = __float2bfloat16(0.f);
    H0b[i] = z; H1b[i] = z;
    if (i < 4096) bar[i] = 0u;
}

__global__ __launch_bounds__(256) void wtmp_k(const float* __restrict__ W3,
                                              const float* __restrict__ W2,
                                              float* __restrict__ Wtmp) {
    int idx = blockIdx.x * 256 + threadIdx.x;
    int j = idx / 512, i = idx % 512;
    float a[8] = {0,0,0,0,0,0,0,0};
    for (int q = 0; q < 1024; q += 8) {
#pragma unroll
        for (int u = 0; u < 8; u++)
            a[u] += W3[j * 1024 + q + u] * W2[(q + u) * 512 + i];
    }
    Wtmp[idx] = ((a[0]+a[1])+(a[2]+a[3])) + ((a[4]+a[5])+(a[6]+a[7]));
}

__global__ __launch_bounds__(256) void weff_k(const float* __restrict__ Wtmp,
                                              const float* __restrict__ W1,
                                              float* __restrict__ Weff) {
    int idx = blockIdx.x * 256 + threadIdx.x;
    if (idx >= 3840) return;
    int j = idx / 384, i = idx % 384;
    float a[8] = {0,0,0,0,0,0,0,0};
    for (int q = 0; q < 512; q += 8) {
#pragma unroll
        for (int u = 0; u < 8; u++)
            a[u] += Wtmp[j * 512 + q + u] * W1[(q + u) * 384 + i];
    }
    Weff[idx] = ((a[0]+a[1])+(a[2]+a[3])) + ((a[4]+a[5])+(a[6]+a[7]));
}

__global__ __launch_bounds__(256) void beff_k(const float* __restrict__ W3, const float* __restrict__ b2,
                       const float* __restrict__ Wtmp, const float* __restrict__ b1,
                       const float* __restrict__ b3, float* __restrict__ beff) {
    __shared__ float red[256];
    int tid = threadIdx.x;
    for (int j = 0; j < 10; j++) {
        float p = 0.f;
        for (int q = tid; q < 1024; q += 256) p += W3[j * 1024 + q] * b2[q];
        for (int q = tid; q < 512; q += 256)  p += Wtmp[j * 512 + q] * b1[q];
        red[tid] = p;
        __syncthreads();
        for (int s = 128; s > 0; s >>= 1) {
            if (tid < s) red[tid] += red[tid + s];
            __syncthreads();
        }
        if (tid == 0) beff[j] = red[0] + b3[j];
        __syncthreads();
    }
}

// ---------------- persistent pipelined LSTM ----------------
// R3 topology (passed, 2333us): 192 blocks = 16 chains (8 groups x 2 layers)
// x 12 gate-blocks. chain c = blockIdx&15: l=c&1, g=c>>1; bsub=blockIdx>>4.
// Deltas vs R3: per-producer 64B-padded flags (no contended counter), relaxed
// polls + s_sleep (no agent-acquire L2-invalidate per spin), L0 barrier trim.

__device__ __forceinline__ bf16x8 lds_frag(const short* As, int r, int k) {
    const short* p = As + r * 388 + k;
    bf16x4 lo = *reinterpret_cast<const bf16x4*>(p);
    bf16x4 hi = *reinterpret_cast<const bf16x4*>(p + 4);
    return __builtin_shufflevector(lo, hi, 0, 1, 2, 3, 4, 5, 6, 7);
}

// stage 32 rows x 384 bf16 (contiguous 24576B) into LDS (row stride 388 shorts)
__device__ __forceinline__ void stage(short* As, const ull* src, int tid) {
#pragma unroll
    for (int i = 0; i < 12; i++) {
        int q = tid + 256 * i;          // 0..3071 (96 ull per row)
        int row = q / 96;
        int c8 = q - row * 96;
        ull v = cload(src + q);
        *reinterpret_cast<ull*>(As + row * 388 + c8 * 4) = v;
    }
}

template<int L>
__device__ void run_chain(
    const __hip_bfloat16* __restrict__ Xb,
    const __hip_bfloat16* __restrict__ Wcat,
    const float* __restrict__ bih, const float* __restrict__ bhh,
    const __hip_bfloat16* __restrict__ Hin,   // L=1: producer's H0
    __hip_bfloat16* __restrict__ Hown,
    unsigned* myflag, const unsigned* ownbase, const unsigned* prodbase,
    short* As1, short* As2, float* gbuf,
    int g, int bsub, int tid)
{
    constexpr int NKI = (L ? 12 : 4);
    constexpr int NK  = NKI + 12;
    constexpr int LDW = (L ? 768 : 512);
    int lane = tid & 63, wv = tid >> 6;
    int lane15 = lane & 15, koff = (lane >> 4) * 8;

    // register-resident weight fragments
    bf16x8 bw[2][NK];
#pragma unroll
    for (int nt = 0; nt < 2; nt++) {
        const __hip_bfloat16* Wrow =
            Wcat + (size_t)(wv * 384 + bsub * 32 + nt * 16 + lane15) * LDW;
#pragma unroll
        for (int kk = 0; kk < NK; kk++)
            bw[nt][kk] = *reinterpret_cast<const bf16x8*>(Wrow + kk * 32 + koff);
    }

    // cell-thread state (m = tid>>3, dims d0..d0+3)
    int m = tid >> 3, d0 = (tid & 7) * 4;
    int dgl = bsub * 32 + d0;
    float bb[4][4];
#pragma unroll
    for (int j = 0; j < 4; j++)
#pragma unroll
        for (int jj = 0; jj < 4; jj++)
            bb[j][jj] = bih[j * 384 + dgl + jj] + bhh[j * 384 + dgl + jj];
    float cst[4] = {0.f, 0.f, 0.f, 0.f};

    const __hip_bfloat16* XbRow = (L == 0) ? (Xb + (size_t)(g * 32 + lane15) * 128 + koff) : nullptr;
    ull* hout = reinterpret_cast<ull*>(Hown + (size_t)(g * 32 + m) * 384 + dgl);
    const char* hsrc_own = reinterpret_cast<const char*>(Hown + (size_t)g * 12288);
    const char* hsrc_in  = L ? reinterpret_cast<const char*>(Hin + (size_t)g * 12288) : nullptr;

    // poll assignment (wave 0): lanes 0..11 -> own flags (need t);
    // L1 lanes 12..23 -> producer flags (need t+1); others -> own flag 0.
    const unsigned* pf = ownbase;
    unsigned addv = 0;
    if (lane < 12) pf = ownbase + lane * 16;
    else if (L == 1 && lane < 24) { pf = prodbase + (lane - 12) * 16; addv = 1; }
    int r0 = (lane >> 4) * 4, ccol = lane15;

#pragma unroll 1
    for (int t = 0; t < 256; t++) {
        // ---- wait: own chain done t-1; L1: producer done t ----
        if (tid < 64) {
            unsigned need = (unsigned)t + addv;
            for (;;) {
                unsigned f = fload(pf);
                if (__ballot(f >= need) == ~0ull) break;
                __builtin_amdgcn_s_sleep(1);
            }
        }
        __syncthreads();
        asm volatile("" ::: "memory");

        floatx4 acc[2][2];
#pragma unroll
        for (int mt = 0; mt < 2; mt++)
#pragma unroll
            for (int nt = 0; nt < 2; nt++) acc[mt][nt] = floatx4{0.f, 0.f, 0.f, 0.f};

        if (L == 0) {
            // Xb fragments + own-h stage; Xb MFMAs issued before the barrier
            bf16x8 ax[2][4];
            const __hip_bfloat16* A1p = XbRow + (size_t)t * 32768;
#pragma unroll
            for (int mt = 0; mt < 2; mt++)
#pragma unroll
                for (int kk = 0; kk < 4; kk++)
                    ax[mt][kk] = *reinterpret_cast<const bf16x8*>(A1p + mt * 2048 + kk * 32);
            stage(As2, reinterpret_cast<const ull*>(hsrc_own + (size_t)t * 196608), tid);
#pragma unroll
            for (int kk = 0; kk < 4; kk++)
#pragma unroll
                for (int mt = 0; mt < 2; mt++) {
                    acc[mt][0] = __builtin_amdgcn_mfma_f32_16x16x32_bf16(ax[mt][kk], bw[0][kk], acc[mt][0], 0, 0, 0);
                    acc[mt][1] = __builtin_amdgcn_mfma_f32_16x16x32_bf16(ax[mt][kk], bw[1][kk], acc[mt][1], 0, 0, 0);
                }
            __syncthreads();
        } else {
            stage(As1, reinterpret_cast<const ull*>(hsrc_in + (size_t)(t + 1) * 196608), tid);
            stage(As2, reinterpret_cast<const ull*>(hsrc_own + (size_t)t * 196608), tid);
            __syncthreads();
#pragma unroll
            for (int kk = 0; kk < 12; kk++)
#pragma unroll
                for (int mt = 0; mt < 2; mt++) {
                    bf16x8 a = lds_frag(As1, mt * 16 + lane15, kk * 32 + koff);
                    acc[mt][0] = __builtin_amdgcn_mfma_f32_16x16x32_bf16(a, bw[0][kk], acc[mt][0], 0, 0, 0);
                    acc[mt][1] = __builtin_amdgcn_mfma_f32_16x16x32_bf16(a, bw[1][kk], acc[mt][1], 0, 0, 0);
                }
        }
#pragma unroll
        for (int kk = 0; kk < 12; kk++)
#pragma unroll
            for (int mt = 0; mt < 2; mt++) {
                bf16x8 a = lds_frag(As2, mt * 16 + lane15, kk * 32 + koff);
                acc[mt][0] = __builtin_amdgcn_mfma_f32_16x16x32_bf16(a, bw[0][NKI + kk], acc[mt][0], 0, 0, 0);
                acc[mt][1] = __builtin_amdgcn_mfma_f32_16x16x32_bf16(a, bw[1][NKI + kk], acc[mt][1], 0, 0, 0);
            }
        if (L == 1) __syncthreads();   // gbuf aliases As1 (L1 read it via MFMA)

        // ---- gates to LDS: C layout row=(lane>>4)*4+r, col=lane&15 ----
#pragma unroll
        for (int mt = 0; mt < 2; mt++)
#pragma unroll
            for (int nt = 0; nt < 2; nt++)
#pragma unroll
                for (int r = 0; r < 4; r++)
                    gbuf[wv * 1056 + (mt * 16 + r0 + r) * 33 + nt * 16 + ccol] = acc[mt][nt][r];
        __syncthreads();

        // ---- cell update + h store ----
        union { ull u; __hip_bfloat16 h[4]; } pk;
#pragma unroll
        for (int jj = 0; jj < 4; jj++) {
            float gi = gbuf[0 * 1056 + m * 33 + d0 + jj] + bb[0][jj];
            float gf = gbuf[1 * 1056 + m * 33 + d0 + jj] + bb[1][jj];
            float gg = gbuf[2 * 1056 + m * 33 + d0 + jj] + bb[2][jj];
            float go = gbuf[3 * 1056 + m * 33 + d0 + jj] + bb[3][jj];
            float c = fsig(gf) * cst[jj] + fsig(gi) * ftanh(gg);
            cst[jj] = c;
            pk.h[jj] = __float2bfloat16(fsig(go) * ftanh(c));
        }
        cstore(hout + (size_t)(t + 1) * 12288, pk.u);

        __syncthreads();   // compiler emits s_waitcnt vmcnt(0) before s_barrier:
                           // all h stores acked at the coherence point (L3)
        if (tid == 0)
            __hip_atomic_fetch_add(myflag, 1u, __ATOMIC_RELAXED, AGT);
    }
}

__global__ __launch_bounds__(256, 1) void lstm_persistent(
    const __hip_bfloat16* __restrict__ Xb,
    const __hip_bfloat16* __restrict__ Wcat0,
    const __hip_bfloat16* __restrict__ Wcat1,
    const float* __restrict__ bih0, const float* __restrict__ bhh0,
    const float* __restrict__ bih1, const float* __restrict__ bhh1,
    __hip_bfloat16* __restrict__ H0, __hip_bfloat16* __restrict__ H1,
    unsigned* __restrict__ bar)
{
    __shared__ __align__(16) char smem[49664];
    short* As1 = (short*)smem;              // L1 staged h0; aliases gbuf
    short* As2 = (short*)(smem + 24832);    // staged own h
    float* gbuf = (float*)smem;             // phase-disjoint with As1

    int tid = threadIdx.x;
    int c = blockIdx.x & 15;
    int l = c & 1, g = c >> 1;
    int bsub = blockIdx.x >> 4;
    // flags: one 64B line per producer block: flags[(chain*12 + bsub)*16]
    unsigned* flags = bar + 64;
    unsigned* myflag = flags + (c * 12 + bsub) * 16;
    const unsigned* ownbase = flags + c * 12 * 16;
    const unsigned* prodbase = flags + (c ^ 1) * 12 * 16;

    if (l == 0)
        run_chain<0>(Xb, Wcat0, bih0, bhh0, nullptr, H0, myflag, ownbase, nullptr,
                     As1, As2, gbuf, g, bsub, tid);
    else
        run_chain<1>(nullptr, Wcat1, bih1, bhh1, H0, H1, myflag, ownbase, prodbase,
                     As1, As2, gbuf, g, bsub, tid);
}

// ---------------- emissions ----------------
__global__ __launch_bounds__(256) void em_kernel(const __hip_bfloat16* __restrict__ H1,
                                                 const float* __restrict__ Weff,
                                                 const float* __restrict__ beff,
                                                 float* __restrict__ em) {
    __shared__ __hip_bfloat16 At[256 * 68];
    __shared__ float Wt[640];
    __shared__ float bf[10];
    int tid = threadIdx.x;
    int row0 = blockIdx.x * 256;
    if (tid < 10) bf[tid] = beff[tid];
    float acc[10];
#pragma unroll
    for (int j = 0; j < 10; j++) acc[j] = 0.f;

    for (int kt = 0; kt < 384; kt += 64) {
        __syncthreads();
#pragma unroll
        for (int q = 0; q < 16; q++) {
            int flat = q * 256 + tid;
            int r = flat >> 4;
            int k4 = flat & 15;
            const __hip_bfloat16* src = H1 + (size_t)(row0 + r) * 384 + kt + k4 * 4;
            *reinterpret_cast<uint2*>(&At[r * 68 + k4 * 4]) =
                *reinterpret_cast<const uint2*>(src);
        }
        for (int q = tid; q < 640; q += 256) {
            int j = q >> 6, k = q & 63;
            Wt[q] = Weff[j * 384 + kt + k];
        }
        __syncthreads();
        for (int k = 0; k < 64; k++) {
            float a = __bfloat162float(At[tid * 68 + k]);
#pragma unroll
            for (int j = 0; j < 10; j++) acc[j] += a * Wt[j * 64 + k];
        }
    }
#pragma unroll
    for (int j = 0; j < 10; j++) em[(size_t)(row0 + tid) * 10 + j] = acc[j] + bf[j];
}

// ---------------- CRF ----------------
__global__ __launch_bounds__(64) void crf_kernel(const float* __restrict__ em,
                                                 const int* __restrict__ tags,
                                                 const float* __restrict__ start_t,
                                                 const float* __restrict__ end_t,
                                                 const float* __restrict__ trans,
                                                 float* __restrict__ nll) {
    int s = blockIdx.x;
    int l = threadIdx.x;
    __shared__ float tr[100];
    __shared__ float aA[16], aB[16];
    if (l < 100) tr[l] = trans[l];
    if (l < 36)  tr[l + 64] = trans[l + 64];
    __syncthreads();

    float part = 0.f;
    for (int b = l; b < 256; b += 64) {
        int tg = tags[s * 256 + b];
        part += em[(size_t)(s * 256 + b) * 10 + tg];
        if (b > 0) {
            int tp = tags[s * 256 + b - 1];
            part += tr[tp * 10 + tg];
        }
    }
    for (int off = 32; off > 0; off >>= 1) part += __shfl_down(part, off);

    if (l < 10) aA[l] = start_t[l] + em[(size_t)(s * 256) * 10 + l];
    __syncthreads();
    for (int b = 1; b < 256; b++) {
        const float* rb = (b & 1) ? aA : aB;
        float* wb = (b & 1) ? aB : aA;
        if (l < 10) {
            float m = -1e30f;
            for (int i = 0; i < 10; i++) m = fmaxf(m, rb[i] + tr[i * 10 + l]);
            float ssum = 0.f;
            for (int i = 0; i < 10; i++) ssum += __expf(rb[i] + tr[i * 10 + l] - m);
            wb[l] = em[(size_t)(s * 256 + b) * 10 + l] + m + __logf(ssum);
        }
        __syncthreads();
    }
    if (l == 0) {
        const float* af = aB;
        float m = -1e30f;
        for (int i = 0; i < 10; i++) m = fmaxf(m, af[i] + end_t[i]);
        float ssum = 0.f;
        for (int i = 0; i < 10; i++) ssum += __expf(af[i] + end_t[i] - m);
        float logZ = m + __logf(ssum);
        float score = part + start_t[tags[s * 256]] + end_t[tags[s * 256 + 255]];
        nll[s] = logZ - score;
    }
}

__global__ __launch_bounds__(256) void reduce_k(const float* __restrict__ nll,
                                                float* __restrict__ out) {
    __shared__ float sm[256];
    int t = threadIdx.x;
    sm[t] = nll[t];
    __syncthreads();
    for (int s = 128; s > 0; s >>= 1) {
        if (t < s) sm[t] += sm[t + s];
        __syncthreads();
    }
    if (t == 0) out[0] = sm[0];
}

// ---------------- host ----------------

extern "C" void kernel_launch(void* const* d_in, const int* in_sizes, int n_in,
                              void* d_out, int out_size, void* d_ws, size_t ws_size,
                              hipStream_t stream) {
    const float* x     = (const float*)d_in[0];
    const int*   tags  = (const int*)d_in[2];
    const float* Wih0  = (const float*)d_in[3];
    const float* Whh0  = (const float*)d_in[4];
    const float* bih0  = (const float*)d_in[5];
    const float* bhh0  = (const float*)d_in[6];
    const float* Wih1  = (const float*)d_in[7];
    const float* Whh1  = (const float*)d_in[8];
    const float* bih1  = (const float*)d_in[9];
    const float* bhh1  = (const float*)d_in[10];
    const float* W1    = (const float*)d_in[11];
    const float* b1    = (const float*)d_in[12];
    const float* W2    = (const float*)d_in[13];
    const float* b2    = (const float*)d_in[14];
    const float* W3    = (const float*)d_in[15];
    const float* b3    = (const float*)d_in[16];
    const float* start_t = (const float*)d_in[17];
    const float* end_t   = (const float*)d_in[18];
    const float* trans   = (const float*)d_in[19];

    char* ws = (char*)d_ws;
    size_t off = 0;
    auto alloc = [&](size_t bytes) { void* p = ws + off; off += (bytes + 255) & ~(size_t)255; return p; };

    __hip_bfloat16* Xb    = (__hip_bfloat16*)alloc((size_t)65536 * 128 * 2);
    __hip_bfloat16* Wcat0 = (__hip_bfloat16*)alloc((size_t)1536 * 512 * 2);
    __hip_bfloat16* Wcat1 = (__hip_bfloat16*)alloc((size_t)1536 * 768 * 2);
    __hip_bfloat16* H0b   = (__hip_bfloat16*)alloc((size_t)257 * 98304 * 2);
    __hip_bfloat16* H1b   = (__hip_bfloat16*)alloc((size_t)257 * 98304 * 2);
    float* EM   = (float*)alloc((size_t)65536 * 10 * 4);
    float* Wtmp = (float*)alloc((size_t)10 * 512 * 4);
    float* Weff = (float*)alloc((size_t)10 * 384 * 4);
    float* beff = (float*)alloc(256);
    float* nll  = (float*)alloc(256 * 4);
    unsigned* bar = (unsigned*)alloc(4096 * 4);

    // prep
    prep_x<<<4096, 256, 0, stream>>>(x, Xb);
    prep_wcat<<<dim3(2, 1536), 256, 0, stream>>>(Wih0, 100, 128, Whh0, Wcat0, 512);
    prep_wcat<<<dim3(3, 1536), 256, 0, stream>>>(Wih1, 384, 384, Whh1, Wcat1, 768);
    init_zero<<<384, 256, 0, stream>>>(H0b, H1b, bar);
    wtmp_k<<<20, 256, 0, stream>>>(W3, W2, Wtmp);
    weff_k<<<15, 256, 0, stream>>>(Wtmp, W1, Weff);
    beff_k<<<1, 256, 0, stream>>>(W3, b2, Wtmp, b1, b3, beff);

    // persistent LSTM (R3 topology; per-producer padded flags; relaxed polls)
    lstm_persistent<<<192, 256, 0, stream>>>(Xb, Wcat0, Wcat1,
                                             bih0, bhh0, bih1, bhh1,
                                             H0b, H1b, bar);

    // emissions + CRF
    em_kernel<<<256, 256, 0, stream>>>(H1b + 98304, Weff, beff, EM);
    crf_kernel<<<256, 64, 0, stream>>>(EM, tags, start_t, end_t, trans, nll);
    reduce_k<<<1, 256, 0, stream>>>(nll, (float*)d_out);
}

// Round 8
// 1481.852 us; speedup vs baseline: 2.3708x; 1.7691x over previous
//
#include <hip/hip_runtime.h>
#include <hip/hip_bf16.h>

typedef __bf16 bf16x8 __attribute__((ext_vector_type(8)));
typedef __bf16 bf16x4 __attribute__((ext_vector_type(4)));
typedef float floatx4 __attribute__((ext_vector_type(4)));
typedef unsigned long long ull;

#define AGT __HIP_MEMORY_SCOPE_AGENT

// Relaxed agent-scope atomics -> sc1 loads/stores hitting the coherent L3,
// bypassing non-coherent L1/L2. No acquire/release in hot loops.
__device__ __forceinline__ ull cload(const ull* p) {
    return __hip_atomic_load(const_cast<ull*>(p), __ATOMIC_RELAXED, AGT);
}
__device__ __forceinline__ void cstore32(unsigned* p, unsigned v) {
    __hip_atomic_store(p, v, __ATOMIC_RELAXED, AGT);
}
__device__ __forceinline__ unsigned fload(const unsigned* p) {
    return __hip_atomic_load(const_cast<unsigned*>(p), __ATOMIC_RELAXED, AGT);
}
__device__ __forceinline__ float fsig(float x) { return 1.f / (1.f + __expf(-x)); }
__device__ __forceinline__ float ftanh(float x) { return 1.f - 2.f / (__expf(2.f * x) + 1.f); }

// ---------------- prep kernels ----------------

__global__ __launch_bounds__(256) void prep_x(const float* __restrict__ x,
                                              __hip_bfloat16* __restrict__ Xb) {
    int t = blockIdx.x * 256 + threadIdx.x;
    int row = t >> 4, c8 = (t & 15) * 8;
    union { __hip_bfloat16 h[8]; uint4 u; } pk;
#pragma unroll
    for (int j = 0; j < 8; j++) {
        int col = c8 + j;
        float v = (col < 100) ? x[row * 100 + col] : 0.f;
        pk.h[j] = __float2bfloat16(v);
    }
    *reinterpret_cast<uint4*>(Xb + (size_t)row * 128 + c8) = pk.u;
}

__global__ __launch_bounds__(256) void prep_wcat(const float* __restrict__ Wih, int Kin, int K1,
                                                 const float* __restrict__ Whh,
                                                 __hip_bfloat16* __restrict__ Wcat, int ldW) {
    int k = blockIdx.x * 256 + threadIdx.x;
    int row = blockIdx.y;
    if (k >= ldW) return;
    float v;
    if (k < K1) v = (k < Kin) ? Wih[row * Kin + k] : 0.f;
    else        v = Whh[row * 384 + (k - K1)];
    Wcat[row * ldW + k] = __float2bfloat16(v);
}

__global__ __launch_bounds__(256) void init_zero(__hip_bfloat16* __restrict__ H0b,
                                                 __hip_bfloat16* __restrict__ H1b,
                                                 unsigned* __restrict__ bar) {
    int i = blockIdx.x * 256 + threadIdx.x;
    __hip_bfloat16 z = __float2bfloat16(0.f);
    H0b[i] = z; H1b[i] = z;
    if (i < 4096) bar[i] = 0u;
}

__global__ __launch_bounds__(256) void wtmp_k(const float* __restrict__ W3,
                                              const float* __restrict__ W2,
                                              float* __restrict__ Wtmp) {
    int idx = blockIdx.x * 256 + threadIdx.x;
    int j = idx / 512, i = idx % 512;
    float a[8] = {0,0,0,0,0,0,0,0};
    for (int q = 0; q < 1024; q += 8) {
#pragma unroll
        for (int u = 0; u < 8; u++)
            a[u] += W3[j * 1024 + q + u] * W2[(q + u) * 512 + i];
    }
    Wtmp[idx] = ((a[0]+a[1])+(a[2]+a[3])) + ((a[4]+a[5])+(a[6]+a[7]));
}

__global__ __launch_bounds__(256) void weff_k(const float* __restrict__ Wtmp,
                                              const float* __restrict__ W1,
                                              float* __restrict__ Weff) {
    int idx = blockIdx.x * 256 + threadIdx.x;
    if (idx >= 3840) return;
    int j = idx / 384, i = idx % 384;
    float a[8] = {0,0,0,0,0,0,0,0};
    for (int q = 0; q < 512; q += 8) {
#pragma unroll
        for (int u = 0; u < 8; u++)
            a[u] += Wtmp[j * 512 + q + u] * W1[(q + u) * 384 + i];
    }
    Weff[idx] = ((a[0]+a[1])+(a[2]+a[3])) + ((a[4]+a[5])+(a[6]+a[7]));
}

__global__ __launch_bounds__(256) void beff_k(const float* __restrict__ W3, const float* __restrict__ b2,
                       const float* __restrict__ Wtmp, const float* __restrict__ b1,
                       const float* __restrict__ b3, float* __restrict__ beff) {
    __shared__ float red[256];
    int tid = threadIdx.x;
    for (int j = 0; j < 10; j++) {
        float p = 0.f;
        for (int q = tid; q < 1024; q += 256) p += W3[j * 1024 + q] * b2[q];
        for (int q = tid; q < 512; q += 256)  p += Wtmp[j * 512 + q] * b1[q];
        red[tid] = p;
        __syncthreads();
        for (int s = 128; s > 0; s >>= 1) {
            if (tid < s) red[tid] += red[tid + s];
            __syncthreads();
        }
        if (tid == 0) beff[j] = red[0] + b3[j];
        __syncthreads();
    }
}

// ---------------- persistent pipelined LSTM (512-thread blocks) ----------------
// 192 blocks = 16 chains (8 groups x 2 layers) x 12 gate-blocks, 512 thr each.
// 8 waves/block: wave w -> gate (w&3), nt-half (w>>2). Per-wave weight frags:
// L0 16, L1 24 (x4 VGPR = 64/96) -> fits registers (R3/R7 at 256 thr needed
// 192 VGPR of weights and the compiler rematerialized from L2 every step:
// VGPR_Count=144 evidence). __launch_bounds__(512,2) caps VGPR at 256 ->
// 2 waves/SIMD -> 1 block/CU -> all 192 co-resident.

__device__ __forceinline__ bf16x8 lds_frag(const short* As, int r, int k) {
    const short* p = As + r * 388 + k;
    bf16x4 lo = *reinterpret_cast<const bf16x4*>(p);
    bf16x4 hi = *reinterpret_cast<const bf16x4*>(p + 4);
    return __builtin_shufflevector(lo, hi, 0, 1, 2, 3, 4, 5, 6, 7);
}

// stage 32 rows x 384 bf16 (24576B) into LDS (row stride 388 shorts), 512 thr
__device__ __forceinline__ void stage512(short* As, const ull* src, int tid) {
    ull v[6];
#pragma unroll
    for (int i = 0; i < 6; i++) v[i] = cload(src + tid + 512 * i);
#pragma unroll
    for (int i = 0; i < 6; i++) {
        int q = tid + 512 * i;          // 0..3071 (96 ull per row)
        int row = q / 96;
        int c8 = q - row * 96;
        *reinterpret_cast<ull*>(As + row * 388 + c8 * 4) = v[i];
    }
}
// stage two slices, all 12 loads outstanding before scatter
__device__ __forceinline__ void stage512x2(short* Asa, const ull* sa,
                                           short* Asb, const ull* sb, int tid) {
    ull va[6], vb[6];
#pragma unroll
    for (int i = 0; i < 6; i++) va[i] = cload(sa + tid + 512 * i);
#pragma unroll
    for (int i = 0; i < 6; i++) vb[i] = cload(sb + tid + 512 * i);
#pragma unroll
    for (int i = 0; i < 6; i++) {
        int q = tid + 512 * i;
        int row = q / 96;
        int c8 = q - row * 96;
        *reinterpret_cast<ull*>(Asa + row * 388 + c8 * 4) = va[i];
        *reinterpret_cast<ull*>(Asb + row * 388 + c8 * 4) = vb[i];
    }
}

template<int L>
__device__ void run_chain(
    const __hip_bfloat16* __restrict__ Xb,
    const __hip_bfloat16* __restrict__ Wcat,
    const float* __restrict__ bih, const float* __restrict__ bhh,
    const __hip_bfloat16* __restrict__ Hin,   // L=1: producer's H0
    __hip_bfloat16* __restrict__ Hown,
    unsigned* myflag, const unsigned* ownbase, const unsigned* prodbase,
    short* As1, short* As2, float* gbuf,
    int g, int bsub, int tid)
{
    constexpr int NKI = (L ? 12 : 4);
    constexpr int NK  = NKI + 12;
    constexpr int LDW = (L ? 768 : 512);
    int lane = tid & 63, wv = tid >> 6;        // wv 0..7
    int g4 = wv & 3, nt = wv >> 2;             // gate, n-half
    int lane15 = lane & 15, koff = (lane >> 4) * 8;

    // ---- register-resident weight fragments: ONE nt per wave ----
    bf16x8 bw[NK];
    {
        const __hip_bfloat16* Wrow =
            Wcat + (size_t)(g4 * 384 + bsub * 32 + nt * 16 + lane15) * LDW;
#pragma unroll
        for (int kk = 0; kk < NK; kk++)
            bw[kk] = *reinterpret_cast<const bf16x8*>(Wrow + kk * 32 + koff);
    }

    // ---- cell-thread state: m = tid>>4 (0..31), dims d0..d0+1 ----
    int m = tid >> 4, d0 = (tid & 15) * 2;
    int dgl = bsub * 32 + d0;
    float bb[4][2];
#pragma unroll
    for (int j = 0; j < 4; j++)
#pragma unroll
        for (int jj = 0; jj < 2; jj++)
            bb[j][jj] = bih[j * 384 + dgl + jj] + bhh[j * 384 + dgl + jj];
    float cst[2] = {0.f, 0.f};

    const __hip_bfloat16* XbRow = (L == 0) ? (Xb + (size_t)(g * 32 + lane15) * 128 + koff) : nullptr;
    unsigned* hout = reinterpret_cast<unsigned*>(Hown + (size_t)(g * 32 + m) * 384 + dgl);
    const ull* hsrc_own = reinterpret_cast<const ull*>(Hown + (size_t)g * 12288);
    const ull* hsrc_in  = L ? reinterpret_cast<const ull*>(Hin + (size_t)g * 12288) : nullptr;

    // poll assignment (wave 0 only): lanes 0..11 own flags (need t);
    // L1 lanes 12..23 producer flags (need t+1); others own flag 0.
    const unsigned* pf = ownbase;
    unsigned addv = 0;
    if (lane < 12) pf = ownbase + lane * 16;
    else if (L == 1 && lane < 24) { pf = prodbase + (lane - 12) * 16; addv = 1; }
    int r0 = (lane >> 4) * 4, ccol = lane15;

#pragma unroll 1
    for (int t = 0; t < 256; t++) {
        // ---- wait: own chain done t-1; L1: producer done t ----
        if (tid < 64) {
            unsigned need = (unsigned)t + addv;
            for (;;) {
                unsigned f = fload(pf);
                if (__ballot(f >= need) == ~0ull) break;
                __builtin_amdgcn_s_sleep(1);
            }
        }
        __syncthreads();
        asm volatile("" ::: "memory");

        floatx4 acc[2];
        acc[0] = floatx4{0.f, 0.f, 0.f, 0.f};
        acc[1] = floatx4{0.f, 0.f, 0.f, 0.f};

        if (L == 0) {
            // Xb fragments; input-part MFMAs issued before the stage barrier
            bf16x8 ax[2][4];
            const __hip_bfloat16* A1p = XbRow + (size_t)t * 32768;
#pragma unroll
            for (int mt = 0; mt < 2; mt++)
#pragma unroll
                for (int kk = 0; kk < 4; kk++)
                    ax[mt][kk] = *reinterpret_cast<const bf16x8*>(A1p + mt * 2048 + kk * 32);
            stage512(As2, hsrc_own + (size_t)t * 12288, tid);
#pragma unroll
            for (int kk = 0; kk < 4; kk++)
#pragma unroll
                for (int mt = 0; mt < 2; mt++)
                    acc[mt] = __builtin_amdgcn_mfma_f32_16x16x32_bf16(ax[mt][kk], bw[kk], acc[mt], 0, 0, 0);
            __syncthreads();
        } else {
            stage512x2(As1, hsrc_in + (size_t)(t + 1) * 12288,
                       As2, hsrc_own + (size_t)t * 12288, tid);
            __syncthreads();
#pragma unroll
            for (int kk = 0; kk < 12; kk++)
#pragma unroll
                for (int mt = 0; mt < 2; mt++) {
                    bf16x8 a = lds_frag(As1, mt * 16 + lane15, kk * 32 + koff);
                    acc[mt] = __builtin_amdgcn_mfma_f32_16x16x32_bf16(a, bw[kk], acc[mt], 0, 0, 0);
                }
        }
#pragma unroll
        for (int kk = 0; kk < 12; kk++)
#pragma unroll
            for (int mt = 0; mt < 2; mt++) {
                bf16x8 a = lds_frag(As2, mt * 16 + lane15, kk * 32 + koff);
                acc[mt] = __builtin_amdgcn_mfma_f32_16x16x32_bf16(a, bw[NKI + kk], acc[mt], 0, 0, 0);
            }
        if (L == 1) __syncthreads();   // gbuf aliases As1 (read by L1 MFMAs)

        // ---- gates to LDS: C layout row=(lane>>4)*4+r, col=lane&15 ----
#pragma unroll
        for (int mt = 0; mt < 2; mt++)
#pragma unroll
            for (int r = 0; r < 4; r++)
                gbuf[g4 * 1056 + (mt * 16 + r0 + r) * 33 + nt * 16 + ccol] = acc[mt][r];
        __syncthreads();

        // ---- cell update (2 dims/thread) + h store ----
        union { unsigned u; __hip_bfloat16 h[2]; } pk;
#pragma unroll
        for (int jj = 0; jj < 2; jj++) {
            float gi = gbuf[0 * 1056 + m * 33 + d0 + jj] + bb[0][jj];
            float gf = gbuf[1 * 1056 + m * 33 + d0 + jj] + bb[1][jj];
            float gg = gbuf[2 * 1056 + m * 33 + d0 + jj] + bb[2][jj];
            float go = gbuf[3 * 1056 + m * 33 + d0 + jj] + bb[3][jj];
            float c = fsig(gf) * cst[jj] + fsig(gi) * ftanh(gg);
            cst[jj] = c;
            pk.h[jj] = __float2bfloat16(fsig(go) * ftanh(c));
        }
        cstore32(hout + (size_t)(t + 1) * 49152, pk.u);

        __syncthreads();   // vmcnt(0) drained before barrier: h acked at L3
        if (tid == 0)
            __hip_atomic_store(myflag, (unsigned)(t + 1), __ATOMIC_RELAXED, AGT);
    }
}

__global__ __launch_bounds__(512, 2) void lstm_persistent(
    const __hip_bfloat16* __restrict__ Xb,
    const __hip_bfloat16* __restrict__ Wcat0,
    const __hip_bfloat16* __restrict__ Wcat1,
    const float* __restrict__ bih0, const float* __restrict__ bhh0,
    const float* __restrict__ bih1, const float* __restrict__ bhh1,
    __hip_bfloat16* __restrict__ H0, __hip_bfloat16* __restrict__ H1,
    unsigned* __restrict__ bar)
{
    __shared__ __align__(16) char smem[49664];
    short* As1 = (short*)smem;              // L1 staged h0; aliases gbuf
    short* As2 = (short*)(smem + 24832);    // staged own h
    float* gbuf = (float*)smem;             // phase-disjoint with As1

    int tid = threadIdx.x;
    int c = blockIdx.x & 15;
    int l = c & 1, g = c >> 1;
    int bsub = blockIdx.x >> 4;
    unsigned* flags = bar + 64;
    unsigned* myflag = flags + (c * 12 + bsub) * 16;
    const unsigned* ownbase = flags + c * 12 * 16;
    const unsigned* prodbase = flags + (c ^ 1) * 12 * 16;

    if (l == 0)
        run_chain<0>(Xb, Wcat0, bih0, bhh0, nullptr, H0, myflag, ownbase, nullptr,
                     As1, As2, gbuf, g, bsub, tid);
    else
        run_chain<1>(nullptr, Wcat1, bih1, bhh1, H0, H1, myflag, ownbase, prodbase,
                     As1, As2, gbuf, g, bsub, tid);
}

// ---------------- emissions ----------------
__global__ __launch_bounds__(256) void em_kernel(const __hip_bfloat16* __restrict__ H1,
                                                 const float* __restrict__ Weff,
                                                 const float* __restrict__ beff,
                                                 float* __restrict__ em) {
    __shared__ __hip_bfloat16 At[256 * 68];
    __shared__ float Wt[640];
    __shared__ float bf[10];
    int tid = threadIdx.x;
    int row0 = blockIdx.x * 256;
    if (tid < 10) bf[tid] = beff[tid];
    float acc[10];
#pragma unroll
    for (int j = 0; j < 10; j++) acc[j] = 0.f;

    for (int kt = 0; kt < 384; kt += 64) {
        __syncthreads();
#pragma unroll
        for (int q = 0; q < 16; q++) {
            int flat = q * 256 + tid;
            int r = flat >> 4;
            int k4 = flat & 15;
            const __hip_bfloat16* src = H1 + (size_t)(row0 + r) * 384 + kt + k4 * 4;
            *reinterpret_cast<uint2*>(&At[r * 68 + k4 * 4]) =
                *reinterpret_cast<const uint2*>(src);
        }
        for (int q = tid; q < 640; q += 256) {
            int j = q >> 6, k = q & 63;
            Wt[q] = Weff[j * 384 + kt + k];
        }
        __syncthreads();
        for (int k = 0; k < 64; k++) {
            float a = __bfloat162float(At[tid * 68 + k]);
#pragma unroll
            for (int j = 0; j < 10; j++) acc[j] += a * Wt[j * 64 + k];
        }
    }
#pragma unroll
    for (int j = 0; j < 10; j++) em[(size_t)(row0 + tid) * 10 + j] = acc[j] + bf[j];
}

// ---------------- CRF ----------------
__global__ __launch_bounds__(64) void crf_kernel(const float* __restrict__ em,
                                                 const int* __restrict__ tags,
                                                 const float* __restrict__ start_t,
                                                 const float* __restrict__ end_t,
                                                 const float* __restrict__ trans,
                                                 float* __restrict__ nll) {
    int s = blockIdx.x;
    int l = threadIdx.x;
    __shared__ float tr[100];
    __shared__ float aA[16], aB[16];
    if (l < 100) tr[l] = trans[l];
    if (l < 36)  tr[l + 64] = trans[l + 64];
    __syncthreads();

    float part = 0.f;
    for (int b = l; b < 256; b += 64) {
        int tg = tags[s * 256 + b];
        part += em[(size_t)(s * 256 + b) * 10 + tg];
        if (b > 0) {
            int tp = tags[s * 256 + b - 1];
            part += tr[tp * 10 + tg];
        }
    }
    for (int off = 32; off > 0; off >>= 1) part += __shfl_down(part, off);

    if (l < 10) aA[l] = start_t[l] + em[(size_t)(s * 256) * 10 + l];
    __syncthreads();
    for (int b = 1; b < 256; b++) {
        const float* rb = (b & 1) ? aA : aB;
        float* wb = (b & 1) ? aB : aA;
        if (l < 10) {
            float m = -1e30f;
            for (int i = 0; i < 10; i++) m = fmaxf(m, rb[i] + tr[i * 10 + l]);
            float ssum = 0.f;
            for (int i = 0; i < 10; i++) ssum += __expf(rb[i] + tr[i * 10 + l] - m);
            wb[l] = em[(size_t)(s * 256 + b) * 10 + l] + m + __logf(ssum);
        }
        __syncthreads();
    }
    if (l == 0) {
        const float* af = aB;
        float m = -1e30f;
        for (int i = 0; i < 10; i++) m = fmaxf(m, af[i] + end_t[i]);
        float ssum = 0.f;
        for (int i = 0; i < 10; i++) ssum += __expf(af[i] + end_t[i] - m);
        float logZ = m + __logf(ssum);
        float score = part + start_t[tags[s * 256]] + end_t[tags[s * 256 + 255]];
        nll[s] = logZ - score;
    }
}

__global__ __launch_bounds__(256) void reduce_k(const float* __restrict__ nll,
                                                float* __restrict__ out) {
    __shared__ float sm[256];
    int t = threadIdx.x;
    sm[t] = nll[t];
    __syncthreads();
    for (int s = 128; s > 0; s >>= 1) {
        if (t < s) sm[t] += sm[t + s];
        __syncthreads();
    }
    if (t == 0) out[0] = sm[0];
}

// ---------------- host ----------------

extern "C" void kernel_launch(void* const* d_in, const int* in_sizes, int n_in,
                              void* d_out, int out_size, void* d_ws, size_t ws_size,
                              hipStream_t stream) {
    const float* x     = (const float*)d_in[0];
    const int*   tags  = (const int*)d_in[2];
    const float* Wih0  = (const float*)d_in[3];
    const float* Whh0  = (const float*)d_in[4];
    const float* bih0  = (const float*)d_in[5];
    const float* bhh0  = (const float*)d_in[6];
    const float* Wih1  = (const float*)d_in[7];
    const float* Whh1  = (const float*)d_in[8];
    const float* bih1  = (const float*)d_in[9];
    const float* bhh1  = (const float*)d_in[10];
    const float* W1    = (const float*)d_in[11];
    const float* b1    = (const float*)d_in[12];
    const float* W2    = (const float*)d_in[13];
    const float* b2    = (const float*)d_in[14];
    const float* W3    = (const float*)d_in[15];
    const float* b3    = (const float*)d_in[16];
    const float* start_t = (const float*)d_in[17];
    const float* end_t   = (const float*)d_in[18];
    const float* trans   = (const float*)d_in[19];

    char* ws = (char*)d_ws;
    size_t off = 0;
    auto alloc = [&](size_t bytes) { void* p = ws + off; off += (bytes + 255) & ~(size_t)255; return p; };

    __hip_bfloat16* Xb    = (__hip_bfloat16*)alloc((size_t)65536 * 128 * 2);
    __hip_bfloat16* Wcat0 = (__hip_bfloat16*)alloc((size_t)1536 * 512 * 2);
    __hip_bfloat16* Wcat1 = (__hip_bfloat16*)alloc((size_t)1536 * 768 * 2);
    __hip_bfloat16* H0b   = (__hip_bfloat16*)alloc((size_t)257 * 98304 * 2);
    __hip_bfloat16* H1b   = (__hip_bfloat16*)alloc((size_t)257 * 98304 * 2);
    float* EM   = (float*)alloc((size_t)65536 * 10 * 4);
    float* Wtmp = (float*)alloc((size_t)10 * 512 * 4);
    float* Weff = (float*)alloc((size_t)10 * 384 * 4);
    float* beff = (float*)alloc(256);
    float* nll  = (float*)alloc(256 * 4);
    unsigned* bar = (unsigned*)alloc(4096 * 4);

    // prep
    prep_x<<<4096, 256, 0, stream>>>(x, Xb);
    prep_wcat<<<dim3(2, 1536), 256, 0, stream>>>(Wih0, 100, 128, Whh0, Wcat0, 512);
    prep_wcat<<<dim3(3, 1536), 256, 0, stream>>>(Wih1, 384, 384, Whh1, Wcat1, 768);
    init_zero<<<384, 256, 0, stream>>>(H0b, H1b, bar);
    wtmp_k<<<20, 256, 0, stream>>>(W3, W2, Wtmp);
    weff_k<<<15, 256, 0, stream>>>(Wtmp, W1, Weff);
    beff_k<<<1, 256, 0, stream>>>(W3, b2, Wtmp, b1, b3, beff);

    // persistent LSTM: 192 x 512-thread blocks, register-resident weights
    lstm_persistent<<<192, 512, 0, stream>>>(Xb, Wcat0, Wcat1,
                                             bih0, bhh0, bih1, bhh1,
                                             H0b, H1b, bar);

    // emissions + CRF
    em_kernel<<<256, 256, 0, stream>>>(H1b + 98304, Weff, beff, EM);
    crf_kernel<<<256, 64, 0, stream>>>(EM, tags, start_t, end_t, trans, nll);
    reduce_k<<<1, 256, 0, stream>>>(nll, (float*)d_out);
}